// Round 8
// baseline (548.664 us; speedup 1.0000x reference)
//
#include <hip/hip_runtime.h>
#include <stdint.h>

#define B_ 4
#define T_ 2048
#define D_ 1024
#define H_ 16
#define HD_ 64
#define DFF_ 4096
#define M_ (B_ * T_)  // 8192

typedef __bf16 bf16x8 __attribute__((ext_vector_type(8)));
typedef float f32x4 __attribute__((ext_vector_type(4)));

__device__ __forceinline__ uint16_t f2bf(float f) {
  union { float f; uint32_t u; } v;
  v.f = f;
  uint32_t r = v.u + 0x7FFF + ((v.u >> 16) & 1);  // RNE
  return (uint16_t)(r >> 16);
}

#define GLD_LDS(gp, lp)                                                        \
  __builtin_amdgcn_global_load_lds(                                            \
      (const __attribute__((address_space(1))) void*)(gp),                     \
      (__attribute__((address_space(3))) void*)(lp), 16, 0, 0)

// ---------------- LayerNorm fp32 -> bf16 (used for LN2) ----------------
__global__ __launch_bounds__(256) void ln_bf16(const float* __restrict__ x,
                                               const float* __restrict__ gamma,
                                               const float* __restrict__ beta,
                                               uint16_t* __restrict__ out) {
  __shared__ float red[4];
  const int tid = threadIdx.x;
  const size_t row = blockIdx.x;
  const float4 v = ((const float4*)(x + row * D_))[tid];
  float s = v.x + v.y + v.z + v.w;
#pragma unroll
  for (int off = 32; off >= 1; off >>= 1) s += __shfl_xor(s, off, 64);
  if ((tid & 63) == 0) red[tid >> 6] = s;
  __syncthreads();
  const float mean = (red[0] + red[1] + red[2] + red[3]) * (1.0f / D_);
  const float d0 = v.x - mean, d1 = v.y - mean, d2 = v.z - mean, d3 = v.w - mean;
  float ss = d0 * d0 + d1 * d1 + d2 * d2 + d3 * d3;
#pragma unroll
  for (int off = 32; off >= 1; off >>= 1) ss += __shfl_xor(ss, off, 64);
  __syncthreads();
  if ((tid & 63) == 0) red[tid >> 6] = ss;
  __syncthreads();
  const float var = (red[0] + red[1] + red[2] + red[3]) * (1.0f / D_);
  const float rstd = rsqrtf(var + 1e-5f);
  const float4 g = ((const float4*)gamma)[tid];
  const float4 b = ((const float4*)beta)[tid];
  ushort4 o;
  o.x = f2bf(d0 * rstd * g.x + b.x);
  o.y = f2bf(d1 * rstd * g.y + b.y);
  o.z = f2bf(d2 * rstd * g.z + b.z);
  o.w = f2bf(d3 * rstd * g.w + b.w);
  ((ushort4*)(out + row * D_))[tid] = o;
}

// ---- fused: LN1 (pid<8192) + weight prep (Wo/W1/W2 transposes + qkv rearrange) ----
// Transpose branches vectorized (G13): float4 tile loads + ushort4 transposed
// stores. Values bit-identical to scalar.
__global__ __launch_bounds__(256) void prep_ln(
    const float* __restrict__ x, const float* __restrict__ g1,
    const float* __restrict__ be1, uint16_t* __restrict__ hbuf,
    const float* __restrict__ Wq, const float* __restrict__ Wk,
    const float* __restrict__ Wv, const float* __restrict__ Wo,
    const float* __restrict__ W1, const float* __restrict__ W2,
    uint16_t* __restrict__ wqkvt, uint16_t* __restrict__ wot,
    uint16_t* __restrict__ w1t, uint16_t* __restrict__ w2t) {
  const int pid = blockIdx.x;
  const int tid = threadIdx.x;

  if (pid < 8192) {  // LN1 row
    __shared__ float red[4];
    const size_t row = pid;
    const float4 v = ((const float4*)(x + row * D_))[tid];
    float s = v.x + v.y + v.z + v.w;
#pragma unroll
    for (int off = 32; off >= 1; off >>= 1) s += __shfl_xor(s, off, 64);
    if ((tid & 63) == 0) red[tid >> 6] = s;
    __syncthreads();
    const float mean = (red[0] + red[1] + red[2] + red[3]) * (1.0f / D_);
    const float d0 = v.x - mean, d1 = v.y - mean, d2 = v.z - mean, d3 = v.w - mean;
    float ss = d0 * d0 + d1 * d1 + d2 * d2 + d3 * d3;
#pragma unroll
    for (int off = 32; off >= 1; off >>= 1) ss += __shfl_xor(ss, off, 64);
    __syncthreads();
    if ((tid & 63) == 0) red[tid >> 6] = ss;
    __syncthreads();
    const float var = (red[0] + red[1] + red[2] + red[3]) * (1.0f / D_);
    const float rstd = rsqrtf(var + 1e-5f);
    const float4 g = ((const float4*)g1)[tid];
    const float4 b = ((const float4*)be1)[tid];
    ushort4 o;
    o.x = f2bf(d0 * rstd * g.x + b.x);
    o.y = f2bf(d1 * rstd * g.y + b.y);
    o.z = f2bf(d2 * rstd * g.z + b.z);
    o.w = f2bf(d3 * rstd * g.w + b.w);
    ((ushort4*)(hbuf + row * D_))[tid] = o;
    return;
  }

  __shared__ float tile[32][33];
  const int q = pid - 8192;
  const int row = tid >> 3, c4 = (tid & 7) * 4;  // 32 rows x 8 quads = 256 thr

  if (q >= 9216) {  // qkv rearrange [H][D][HD] -> [which*1024+h*64+e][D]
    const int p = q - 9216;
    const int bx = p & 1, by = (p >> 1) & 31, z = p >> 6;
    const int which = z >> 4, hh = z & 15;
    const float* W = (which == 0) ? Wq : ((which == 1) ? Wk : Wv);
    const float* in = W + (size_t)hh * D_ * HD_;
    const int e0 = bx * 32, d0 = by * 32;
    {
      const float4 v = *(const float4*)(in + (size_t)(d0 + row) * HD_ + e0 + c4);
      tile[row][c4 + 0] = v.x;
      tile[row][c4 + 1] = v.y;
      tile[row][c4 + 2] = v.z;
      tile[row][c4 + 3] = v.w;
    }
    __syncthreads();
    {
      ushort4 o;
      o.x = f2bf(tile[c4 + 0][row]);
      o.y = f2bf(tile[c4 + 1][row]);
      o.z = f2bf(tile[c4 + 2][row]);
      o.w = f2bf(tile[c4 + 3][row]);
      *(ushort4*)(wqkvt + ((size_t)(which * 1024 + hh * 64) + e0 + row) * D_ + d0 +
                  c4) = o;
    }
    return;
  }

  const float* in;
  uint16_t* out;
  int R, C, bx, by;
  if (q < 1024) {
    in = Wo; out = wot; R = 1024; C = 1024; bx = q & 31; by = q >> 5;
  } else if (q < 5120) {
    const int p = q - 1024;
    in = W1; out = w1t; R = 1024; C = 4096; bx = p & 127; by = p >> 7;
  } else {
    const int p = q - 5120;
    in = W2; out = w2t; R = 4096; C = 1024; bx = p & 31; by = p >> 5;
  }
  const int c0 = bx * 32, r0 = by * 32;
  {
    const float4 v = *(const float4*)(in + (size_t)(r0 + row) * C + c0 + c4);
    tile[row][c4 + 0] = v.x;
    tile[row][c4 + 1] = v.y;
    tile[row][c4 + 2] = v.z;
    tile[row][c4 + 3] = v.w;
  }
  __syncthreads();
  {
    ushort4 o;
    o.x = f2bf(tile[c4 + 0][row]);
    o.y = f2bf(tile[c4 + 1][row]);
    o.z = f2bf(tile[c4 + 2][row]);
    o.w = f2bf(tile[c4 + 3][row]);
    *(ushort4*)(out + (size_t)(c0 + row) * R + r0 + c4) = o;
  }
}

// ---------------- bf16 MFMA GEMM: C[M,N] = A[M,K] @ Bt[N,K]^T ----------------
// BM=128, BN template (128 wide-N, 64 for N=1024), BK=64, 4 waves (2x2).
// NEW (T1, m192): bijective XCD chunk swizzle before the GROUP_M raster —
// each XCD gets a contiguous pid chunk, so blocks sharing A/B panels co-reside
// on one XCD's L2 instead of every XCD streaming the full B matrix. Requires
// grid % 8 == 0 (all four call sites: 1536/1024/2048/1024). Kernel is
// latency-bound (MfmaUtil 30%, HBM 24%): higher L2 hit rate shortens the
// per-K-step barrier drain (L2 ~200cy vs HBM ~900cy, m126).
// flags: 1 = relu, 2 = bf16 output
template <int BN>
__global__ __launch_bounds__(256) void gemm_bf16(const uint16_t* __restrict__ A,
                                                 const uint16_t* __restrict__ Bt,
                                                 void* __restrict__ C,
                                                 const float* __restrict__ bias,
                                                 const float* __restrict__ resid,
                                                 int M, int N, int K, int lda,
                                                 int ldb, int flags) {
  constexpr int NJ = BN / 32;  // j-frags per wave
  __shared__ __align__(16) uint16_t As[128 * 64];
  __shared__ __align__(16) uint16_t Bs[BN * 64];
  const int tid = threadIdx.x;
  const int lane = tid & 63, w = tid >> 6;
  const int quad = lane >> 4, lr = lane & 15;
  const int wr = w >> 1, wc = w & 1;

  const int n_tiles = N / BN;
  const int pid0 = blockIdx.x;
  const int cpx = gridDim.x >> 3;  // blocks per XCD chunk (grid % 8 == 0)
  const int pid = (pid0 & 7) * cpx + (pid0 >> 3);
  const int grp = 16 * n_tiles;
  const int gid = pid / grp;
  const int rem = pid - gid * grp;
  const int nt = rem / 16;
  const int mt = gid * 16 + (rem - nt * 16);
  const int bn0 = nt * BN, bm0 = mt * 128;

  f32x4 acc[4][NJ];
#pragma unroll
  for (int i = 0; i < 4; i++)
#pragma unroll
    for (int j = 0; j < NJ; j++) acc[i][j] = f32x4{0.f, 0.f, 0.f, 0.f};

  const int s_row = lane >> 3, s_slot = lane & 7;

  for (int k0 = 0; k0 < K; k0 += 64) {
#pragma unroll
    for (int u = 0; u < 4; u++) {
      const int r = w * 32 + u * 8 + s_row;
      const int cg = s_slot ^ (r & 7);
      GLD_LDS(A + (size_t)(bm0 + r) * lda + k0 + cg * 8, As + (w * 32 + u * 8) * 64);
    }
#pragma unroll
    for (int u = 0; u < NJ; u++) {
      const int r = w * (BN / 4) + u * 8 + s_row;
      const int cg = s_slot ^ (r & 7);
      GLD_LDS(Bt + (size_t)(bn0 + r) * ldb + k0 + cg * 8,
              Bs + (w * (BN / 4) + u * 8) * 64);
    }
    __syncthreads();

#pragma unroll
    for (int ks = 0; ks < 2; ks++) {
      bf16x8 af[4], bfr[NJ];
#pragma unroll
      for (int i = 0; i < 4; i++) {
        const int m = wr * 64 + i * 16 + lr;
        const int slot = (ks * 4 + quad) ^ (m & 7);
        af[i] = *(const bf16x8*)(As + m * 64 + slot * 8);
      }
#pragma unroll
      for (int j = 0; j < NJ; j++) {
        const int n = wc * (BN / 2) + j * 16 + lr;
        const int slot = (ks * 4 + quad) ^ (n & 7);
        bfr[j] = *(const bf16x8*)(Bs + n * 64 + slot * 8);
      }
#pragma unroll
      for (int i = 0; i < 4; i++)
#pragma unroll
        for (int j = 0; j < NJ; j++)
          acc[i][j] =
              __builtin_amdgcn_mfma_f32_16x16x32_bf16(af[i], bfr[j], acc[i][j], 0, 0, 0);
    }
    __syncthreads();
  }

  const int base_m = bm0 + wr * 64 + quad * 4;
  const int base_n = bn0 + wc * (BN / 2) + lr;
#pragma unroll
  for (int i = 0; i < 4; i++) {
#pragma unroll
    for (int j = 0; j < NJ; j++) {
      const int col = base_n + j * 16;
      const float bv = bias ? bias[col] : 0.f;
#pragma unroll
      for (int r = 0; r < 4; r++) {
        const size_t row = base_m + i * 16 + r;
        float v = acc[i][j][r] + bv;
        if (resid) v += resid[row * N + col];
        if (flags & 1) v = fmaxf(v, 0.f);
        if (flags & 2)
          ((uint16_t*)C)[row * N + col] = f2bf(v);
        else
          ((float*)C)[row * N + col] = v;
      }
    }
  }
}

// ---- V transpose: qkv V-region [B*T][3072] -> vtb [(b*H+h)*64+e][T] bf16 ----
__global__ __launch_bounds__(256) void v_transpose(const uint16_t* __restrict__ qkv,
                                                   uint16_t* __restrict__ vtb) {
  __shared__ __align__(16) uint16_t tile[64 * 72];  // [t-local][e]
  const int tid = threadIdx.x;
  const int t0 = blockIdx.x * 64;
  const int bh = blockIdx.y;
  const int b = bh >> 4, h = bh & 15;
  const uint16_t* src = qkv + (size_t)b * T_ * 3072 + 2048 + h * 64;
#pragma unroll
  for (int u = 0; u < 2; u++) {
    const int uu = tid + u * 256;
    const int r = uu >> 3, c = uu & 7;
    *(int4*)(tile + r * 72 + c * 8) =
        *(const int4*)(src + (size_t)(t0 + r) * 3072 + c * 8);
  }
  __syncthreads();
  uint16_t* dst = vtb + ((size_t)bh * 64) * T_ + t0;
#pragma unroll
  for (int u = 0; u < 2; u++) {
    const int uu = tid + u * 256;
    const int e = uu >> 3, c2 = uu & 7;
    union { uint16_t u16[8]; int4 v; } tmp;
#pragma unroll
    for (int jj = 0; jj < 8; jj++) tmp.u16[jj] = tile[(c2 * 8 + jj) * 72 + e];
    *(int4*)(dst + (size_t)e * T_ + c2 * 8) = tmp.v;
  }
}

// ---- per-stage compute for one q-tile (S^T MFMA + static-max softmax + PV) ----
__device__ __forceinline__ void attn_tile_compute(
    const uint16_t* __restrict__ Kb, const uint16_t* __restrict__ Vb,
    uint16_t* __restrict__ Ps, const bf16x8 (&aq)[2][2], f32x4 (&oacc)[2][4],
    float (&l_part)[2], int st, int q0, int w, int quad, int lr) {
  const int lr7 = lr & 7;
  const int row_min_w = q0 + w * 32;

  // S^T = K @ Q^T : frag rows = s (4 sf-frags), cols = m (2 i-frags)
  f32x4 sa[2][4];
#pragma unroll
  for (int i = 0; i < 2; i++)
#pragma unroll
    for (int sf = 0; sf < 4; sf++) sa[i][sf] = f32x4{0.f, 0.f, 0.f, 0.f};
#pragma unroll
  for (int ks = 0; ks < 2; ks++) {
    bf16x8 ak[4];
#pragma unroll
    for (int sf = 0; sf < 4; sf++) {
      const int slot = (ks * 4 + quad) ^ lr7;
      ak[sf] = *(const bf16x8*)(Kb + (sf * 16 + lr) * 64 + slot * 8);
    }
#pragma unroll
    for (int i = 0; i < 2; i++)
#pragma unroll
      for (int sf = 0; sf < 4; sf++)
        sa[i][sf] =
            __builtin_amdgcn_mfma_f32_16x16x32_bf16(ak[sf], aq[i][ks], sa[i][sf], 0, 0, 0);
  }

  // p = exp2(s*log2e/8 - 20*log2e); mask only on the diagonal stage
  const bool diag = (st * 64 + 63 > row_min_w);
  if (diag) {
#pragma unroll
    for (int i = 0; i < 2; i++) {
      const int mrow = q0 + w * 32 + i * 16 + lr;
#pragma unroll
      for (int sf = 0; sf < 4; sf++) {
        const int s0 = st * 64 + sf * 16 + quad * 4;
        float p[4];
#pragma unroll
        for (int r = 0; r < 4; r++) {
          float sv = sa[i][sf][r];
          if (s0 + r > mrow) sv = -1e30f;
          p[r] = exp2f(fmaf(sv, 0.18033688f, -28.8539008f));
          l_part[i] += p[r];
        }
        ushort4 pk;
        pk.x = f2bf(p[0]);
        pk.y = f2bf(p[1]);
        pk.z = f2bf(p[2]);
        pk.w = f2bf(p[3]);
        *(ushort4*)(Ps + (size_t)(w * 32 + i * 16 + lr) * 72 + sf * 16 + quad * 4) = pk;
      }
    }
  } else {
#pragma unroll
    for (int i = 0; i < 2; i++) {
#pragma unroll
      for (int sf = 0; sf < 4; sf++) {
        float p[4];
#pragma unroll
        for (int r = 0; r < 4; r++) {
          p[r] = exp2f(fmaf(sa[i][sf][r], 0.18033688f, -28.8539008f));
          l_part[i] += p[r];
        }
        ushort4 pk;
        pk.x = f2bf(p[0]);
        pk.y = f2bf(p[1]);
        pk.z = f2bf(p[2]);
        pk.w = f2bf(p[3]);
        *(ushort4*)(Ps + (size_t)(w * 32 + i * 16 + lr) * 72 + sf * 16 + quad * 4) = pk;
      }
    }
  }

  // O += P @ V (per-wave LDS region, same-wave write->read)
#pragma unroll
  for (int ks = 0; ks < 2; ks++) {
    bf16x8 ap[2], bv[4];
#pragma unroll
    for (int i = 0; i < 2; i++)
      ap[i] = *(const bf16x8*)(Ps + (size_t)(w * 32 + i * 16 + lr) * 72 + ks * 32 +
                               quad * 8);
#pragma unroll
    for (int j = 0; j < 4; j++) {
      const int slot = (ks * 4 + quad) ^ lr7;
      bv[j] = *(const bf16x8*)(Vb + (j * 16 + lr) * 64 + slot * 8);
    }
#pragma unroll
    for (int i = 0; i < 2; i++)
#pragma unroll
      for (int j = 0; j < 4; j++)
        oacc[i][j] =
            __builtin_amdgcn_mfma_f32_16x16x32_bf16(ap[i], bv[j], oacc[i][j], 0, 0, 0);
  }
}

// ---------------- MFMA flash attention: paired q-tiles + XCD-local K/V ----------
__global__ __launch_bounds__(256) void attn_mfma(const uint16_t* __restrict__ qkv,
                                                 const uint16_t* __restrict__ vtb,
                                                 uint16_t* __restrict__ ctx) {
  __shared__ __align__(16) uint16_t Ks[64 * 64];   // [s][d] swizzled chunks
  __shared__ __align__(16) uint16_t Vt[64 * 64];   // [d][s] swizzled chunks
  __shared__ __align__(16) uint16_t Ps[128 * 72];  // [m][s] plain, padded
  const int tid = threadIdx.x;
  const int lane = tid & 63, w = tid >> 6;
  const int quad = lane >> 4, lr = lane & 15;
  const int pid = blockIdx.x;
  const int bh = pid & 63;         // same XCD for all i of this (b,h)
  const int i_pair = pid >> 6;     // 0..7
  const int b = bh >> 4, h = bh & 15;
  const uint16_t* base = qkv + (size_t)b * T_ * 3072 + h * 64;
  const uint16_t* vbase = vtb + ((size_t)bh * 64) * T_;
  const int s_row = lane >> 3, s_slot = lane & 7;

  const int tqA = i_pair, tqB = 15 - i_pair;
  const int q0A = tqA * 128, q0B = tqB * 128;
  const int nstgA = 2 * tqA + 2, nstgB = 2 * tqB + 2;
  const int nstg = (nstgA > nstgB) ? nstgA : nstgB;

  bf16x8 aqA[2][2], aqB[2][2];
#pragma unroll
  for (int i = 0; i < 2; i++)
#pragma unroll
    for (int ks = 0; ks < 2; ks++) {
      aqA[i][ks] = *(const bf16x8*)(base + (size_t)(q0A + w * 32 + i * 16 + lr) * 3072 +
                                    ks * 32 + quad * 8);
      aqB[i][ks] = *(const bf16x8*)(base + (size_t)(q0B + w * 32 + i * 16 + lr) * 3072 +
                                    ks * 32 + quad * 8);
    }

  f32x4 oaccA[2][4], oaccB[2][4];
#pragma unroll
  for (int i = 0; i < 2; i++)
#pragma unroll
    for (int j = 0; j < 4; j++) {
      oaccA[i][j] = f32x4{0.f, 0.f, 0.f, 0.f};
      oaccB[i][j] = f32x4{0.f, 0.f, 0.f, 0.f};
    }
  float lA[2] = {0.f, 0.f}, lB[2] = {0.f, 0.f};

  const int row_maxA = q0A + w * 32 + 31;
  const int row_maxB = q0B + w * 32 + 31;

  for (int st = 0; st < nstg; st++) {
    __syncthreads();  // prior stage's LDS reads complete
#pragma unroll
    for (int u = 0; u < 2; u++) {
      const int r = w * 16 + u * 8 + s_row;
      const int cg = s_slot ^ (r & 7);
      GLD_LDS(base + 1024 + (size_t)(st * 64 + r) * 3072 + cg * 8,
              Ks + (w * 16 + u * 8) * 64);
      GLD_LDS(vbase + (size_t)r * T_ + st * 64 + cg * 8, Vt + (w * 16 + u * 8) * 64);
    }
    __syncthreads();

    if (st < nstgA && st * 64 <= row_maxA)
      attn_tile_compute(Ks, Vt, Ps, aqA, oaccA, lA, st, q0A, w, quad, lr);
    if (st < nstgB && st * 64 <= row_maxB)
      attn_tile_compute(Ks, Vt, Ps, aqB, oaccB, lB, st, q0B, w, quad, lr);
  }

  // epilogue: reduce l, normalize, store both q-tiles
#pragma unroll
  for (int half = 0; half < 2; half++) {
    const int q0 = half ? q0B : q0A;
    f32x4(&oacc)[2][4] = half ? oaccB : oaccA;
    float* l_part = half ? lB : lA;
    float linv[2];
#pragma unroll
    for (int i = 0; i < 2; i++) {
      float l = l_part[i];
      l += __shfl_xor(l, 16, 64);
      l += __shfl_xor(l, 32, 64);
      linv[i] = 1.f / l;
    }
    uint16_t* ob =
        ctx + ((size_t)b * T_ + q0 + w * 32 + quad * 4) * D_ + h * 64 + lr;
#pragma unroll
    for (int i = 0; i < 2; i++)
#pragma unroll
      for (int r = 0; r < 4; r++) {
        const float inv = __shfl(linv[i], quad * 4 + r, 64);
#pragma unroll
        for (int j = 0; j < 4; j++)
          ob[(size_t)(i * 16 + r) * D_ + j * 16] = f2bf(oacc[i][j][r] * inv);
      }
  }
}

extern "C" void kernel_launch(void* const* d_in, const int* in_sizes, int n_in,
                              void* d_out, int out_size, void* d_ws, size_t ws_size,
                              hipStream_t stream) {
  const float* x = (const float*)d_in[0];
  const float* Wq = (const float*)d_in[1];
  const float* Wk = (const float*)d_in[2];
  const float* Wv = (const float*)d_in[3];
  const float* Wo = (const float*)d_in[4];
  const float* bo = (const float*)d_in[5];
  const float* W1 = (const float*)d_in[6];
  const float* b1 = (const float*)d_in[7];
  const float* W2 = (const float*)d_in[8];
  const float* b2 = (const float*)d_in[9];
  const float* g1 = (const float*)d_in[10];
  const float* be1 = (const float*)d_in[11];
  const float* g2 = (const float*)d_in[12];
  const float* be2 = (const float*)d_in[13];
  float* out = (float*)d_out;

  const size_t MB = 1024ull * 1024ull;
  if (ws_size < 200 * MB) return;
  char* ws = (char*)d_ws;
  uint16_t* hbuf = (uint16_t*)(ws + 0 * MB);    // 16 MB (LN out, reused)
  uint16_t* wqkvt = (uint16_t*)(ws + 16 * MB);  // 6 MB  [3072][1024]
  uint16_t* wot = (uint16_t*)(ws + 22 * MB);    // 2 MB  [1024][1024]
  uint16_t* w1t = (uint16_t*)(ws + 24 * MB);    // 8 MB  [4096][1024]
  uint16_t* w2t = (uint16_t*)(ws + 32 * MB);    // 8 MB  [1024][4096]
  float* x1 = (float*)(ws + 40 * MB);           // 32 MB
  uint16_t* qkvb = (uint16_t*)(ws + 72 * MB);   // 48 MB [8192][3072]
  uint16_t* ctxb = (uint16_t*)(ws + 120 * MB);  // 16 MB [8192][1024]
  uint16_t* vtb = (uint16_t*)(ws + 136 * MB);   // 16 MB (dead before ffb written)
  uint16_t* ffb = (uint16_t*)(ws + 136 * MB);   // 64 MB [8192][4096]

  prep_ln<<<20480, 256, 0, stream>>>(x, g1, be1, hbuf, Wq, Wk, Wv, Wo, W1, W2,
                                     wqkvt, wot, w1t, w2t);
  gemm_bf16<128><<<64 * 24, 256, 0, stream>>>(hbuf, wqkvt, qkvb, nullptr, nullptr,
                                              M_, 3 * D_, D_, D_, D_, 2);
  v_transpose<<<dim3(T_ / 64, B_ * H_), 256, 0, stream>>>(qkvb, vtb);
  attn_mfma<<<512, 256, 0, stream>>>(qkvb, vtb, ctxb);
  gemm_bf16<64><<<64 * 16, 256, 0, stream>>>(ctxb, wot, x1, bo, x, M_, D_, D_, D_,
                                             D_, 0);
  ln_bf16<<<M_, 256, 0, stream>>>(x1, g2, be2, hbuf);
  gemm_bf16<128><<<64 * 32, 256, 0, stream>>>(hbuf, w1t, ffb, b1, nullptr, M_, DFF_,
                                              D_, D_, D_, 1 | 2);
  gemm_bf16<64><<<64 * 16, 256, 0, stream>>>(ffb, w2t, out, b2, x1, M_, D_, DFF_,
                                             DFF_, DFF_, 0);
}

// Round 9
// 515.889 us; speedup vs baseline: 1.0635x; 1.0635x over previous
//
#include <hip/hip_runtime.h>
#include <stdint.h>

#define B_ 4
#define T_ 2048
#define D_ 1024
#define H_ 16
#define HD_ 64
#define DFF_ 4096
#define M_ (B_ * T_)  // 8192

typedef __bf16 bf16x8 __attribute__((ext_vector_type(8)));
typedef float f32x4 __attribute__((ext_vector_type(4)));

__device__ __forceinline__ uint16_t f2bf(float f) {
  union { float f; uint32_t u; } v;
  v.f = f;
  uint32_t r = v.u + 0x7FFF + ((v.u >> 16) & 1);  // RNE
  return (uint16_t)(r >> 16);
}

#define GLD_LDS(gp, lp)                                                        \
  __builtin_amdgcn_global_load_lds(                                            \
      (const __attribute__((address_space(1))) void*)(gp),                     \
      (__attribute__((address_space(3))) void*)(lp), 16, 0, 0)

// ---------------- LayerNorm fp32 -> bf16 (used for LN2) ----------------
__global__ __launch_bounds__(256) void ln_bf16(const float* __restrict__ x,
                                               const float* __restrict__ gamma,
                                               const float* __restrict__ beta,
                                               uint16_t* __restrict__ out) {
  __shared__ float red[4];
  const int tid = threadIdx.x;
  const size_t row = blockIdx.x;
  const float4 v = ((const float4*)(x + row * D_))[tid];
  float s = v.x + v.y + v.z + v.w;
#pragma unroll
  for (int off = 32; off >= 1; off >>= 1) s += __shfl_xor(s, off, 64);
  if ((tid & 63) == 0) red[tid >> 6] = s;
  __syncthreads();
  const float mean = (red[0] + red[1] + red[2] + red[3]) * (1.0f / D_);
  const float d0 = v.x - mean, d1 = v.y - mean, d2 = v.z - mean, d3 = v.w - mean;
  float ss = d0 * d0 + d1 * d1 + d2 * d2 + d3 * d3;
#pragma unroll
  for (int off = 32; off >= 1; off >>= 1) ss += __shfl_xor(ss, off, 64);
  __syncthreads();
  if ((tid & 63) == 0) red[tid >> 6] = ss;
  __syncthreads();
  const float var = (red[0] + red[1] + red[2] + red[3]) * (1.0f / D_);
  const float rstd = rsqrtf(var + 1e-5f);
  const float4 g = ((const float4*)gamma)[tid];
  const float4 b = ((const float4*)beta)[tid];
  ushort4 o;
  o.x = f2bf(d0 * rstd * g.x + b.x);
  o.y = f2bf(d1 * rstd * g.y + b.y);
  o.z = f2bf(d2 * rstd * g.z + b.z);
  o.w = f2bf(d3 * rstd * g.w + b.w);
  ((ushort4*)(out + row * D_))[tid] = o;
}

// ---- fused: LN1 (pid<8192) + weight prep (Wo/W1/W2 transposes + qkv rearrange) ----
// Transpose branches vectorized (G13): float4 tile loads + ushort4 transposed
// stores. Values bit-identical to scalar.
__global__ __launch_bounds__(256) void prep_ln(
    const float* __restrict__ x, const float* __restrict__ g1,
    const float* __restrict__ be1, uint16_t* __restrict__ hbuf,
    const float* __restrict__ Wq, const float* __restrict__ Wk,
    const float* __restrict__ Wv, const float* __restrict__ Wo,
    const float* __restrict__ W1, const float* __restrict__ W2,
    uint16_t* __restrict__ wqkvt, uint16_t* __restrict__ wot,
    uint16_t* __restrict__ w1t, uint16_t* __restrict__ w2t) {
  const int pid = blockIdx.x;
  const int tid = threadIdx.x;

  if (pid < 8192) {  // LN1 row
    __shared__ float red[4];
    const size_t row = pid;
    const float4 v = ((const float4*)(x + row * D_))[tid];
    float s = v.x + v.y + v.z + v.w;
#pragma unroll
    for (int off = 32; off >= 1; off >>= 1) s += __shfl_xor(s, off, 64);
    if ((tid & 63) == 0) red[tid >> 6] = s;
    __syncthreads();
    const float mean = (red[0] + red[1] + red[2] + red[3]) * (1.0f / D_);
    const float d0 = v.x - mean, d1 = v.y - mean, d2 = v.z - mean, d3 = v.w - mean;
    float ss = d0 * d0 + d1 * d1 + d2 * d2 + d3 * d3;
#pragma unroll
    for (int off = 32; off >= 1; off >>= 1) ss += __shfl_xor(ss, off, 64);
    __syncthreads();
    if ((tid & 63) == 0) red[tid >> 6] = ss;
    __syncthreads();
    const float var = (red[0] + red[1] + red[2] + red[3]) * (1.0f / D_);
    const float rstd = rsqrtf(var + 1e-5f);
    const float4 g = ((const float4*)g1)[tid];
    const float4 b = ((const float4*)be1)[tid];
    ushort4 o;
    o.x = f2bf(d0 * rstd * g.x + b.x);
    o.y = f2bf(d1 * rstd * g.y + b.y);
    o.z = f2bf(d2 * rstd * g.z + b.z);
    o.w = f2bf(d3 * rstd * g.w + b.w);
    ((ushort4*)(hbuf + row * D_))[tid] = o;
    return;
  }

  __shared__ float tile[32][33];
  const int q = pid - 8192;
  const int row = tid >> 3, c4 = (tid & 7) * 4;  // 32 rows x 8 quads = 256 thr

  if (q >= 9216) {  // qkv rearrange [H][D][HD] -> [which*1024+h*64+e][D]
    const int p = q - 9216;
    const int bx = p & 1, by = (p >> 1) & 31, z = p >> 6;
    const int which = z >> 4, hh = z & 15;
    const float* W = (which == 0) ? Wq : ((which == 1) ? Wk : Wv);
    const float* in = W + (size_t)hh * D_ * HD_;
    const int e0 = bx * 32, d0 = by * 32;
    {
      const float4 v = *(const float4*)(in + (size_t)(d0 + row) * HD_ + e0 + c4);
      tile[row][c4 + 0] = v.x;
      tile[row][c4 + 1] = v.y;
      tile[row][c4 + 2] = v.z;
      tile[row][c4 + 3] = v.w;
    }
    __syncthreads();
    {
      ushort4 o;
      o.x = f2bf(tile[c4 + 0][row]);
      o.y = f2bf(tile[c4 + 1][row]);
      o.z = f2bf(tile[c4 + 2][row]);
      o.w = f2bf(tile[c4 + 3][row]);
      *(ushort4*)(wqkvt + ((size_t)(which * 1024 + hh * 64) + e0 + row) * D_ + d0 +
                  c4) = o;
    }
    return;
  }

  const float* in;
  uint16_t* out;
  int R, C, bx, by;
  if (q < 1024) {
    in = Wo; out = wot; R = 1024; C = 1024; bx = q & 31; by = q >> 5;
  } else if (q < 5120) {
    const int p = q - 1024;
    in = W1; out = w1t; R = 1024; C = 4096; bx = p & 127; by = p >> 7;
  } else {
    const int p = q - 5120;
    in = W2; out = w2t; R = 4096; C = 1024; bx = p & 31; by = p >> 5;
  }
  const int c0 = bx * 32, r0 = by * 32;
  {
    const float4 v = *(const float4*)(in + (size_t)(r0 + row) * C + c0 + c4);
    tile[row][c4 + 0] = v.x;
    tile[row][c4 + 1] = v.y;
    tile[row][c4 + 2] = v.z;
    tile[row][c4 + 3] = v.w;
  }
  __syncthreads();
  {
    ushort4 o;
    o.x = f2bf(tile[c4 + 0][row]);
    o.y = f2bf(tile[c4 + 1][row]);
    o.z = f2bf(tile[c4 + 2][row]);
    o.w = f2bf(tile[c4 + 3][row]);
    *(ushort4*)(out + (size_t)(c0 + row) * R + r0 + c4) = o;
  }
}

// ---------------- bf16 MFMA GEMM: C[M,N] = A[M,K] @ Bt[N,K]^T ----------------
// BM=128, BN template (128 wide-N, 64 for N=1024), BK=64, 4 waves (2x2).
// GROUP_M=16 grouped raster, DEFAULT dispatch order (XCD chunk swizzle measured
// -31us in r8: it concentrated 16 A-panels (16MB at K=4096) per XCD's 4MB L2
// -> thrash, FETCH 97->142MB; default round-robin + L3 absorption is better
// for this raster geometry). XOR chunk swizzle: 2-way LDS aliasing (free).
// flags: 1 = relu, 2 = bf16 output
template <int BN>
__global__ __launch_bounds__(256) void gemm_bf16(const uint16_t* __restrict__ A,
                                                 const uint16_t* __restrict__ Bt,
                                                 void* __restrict__ C,
                                                 const float* __restrict__ bias,
                                                 const float* __restrict__ resid,
                                                 int M, int N, int K, int lda,
                                                 int ldb, int flags) {
  constexpr int NJ = BN / 32;  // j-frags per wave
  __shared__ __align__(16) uint16_t As[128 * 64];
  __shared__ __align__(16) uint16_t Bs[BN * 64];
  const int tid = threadIdx.x;
  const int lane = tid & 63, w = tid >> 6;
  const int quad = lane >> 4, lr = lane & 15;
  const int wr = w >> 1, wc = w & 1;

  const int n_tiles = N / BN;
  const int pid = blockIdx.x;
  const int grp = 16 * n_tiles;
  const int gid = pid / grp;
  const int rem = pid - gid * grp;
  const int nt = rem / 16;
  const int mt = gid * 16 + (rem - nt * 16);
  const int bn0 = nt * BN, bm0 = mt * 128;

  f32x4 acc[4][NJ];
#pragma unroll
  for (int i = 0; i < 4; i++)
#pragma unroll
    for (int j = 0; j < NJ; j++) acc[i][j] = f32x4{0.f, 0.f, 0.f, 0.f};

  const int s_row = lane >> 3, s_slot = lane & 7;

  for (int k0 = 0; k0 < K; k0 += 64) {
#pragma unroll
    for (int u = 0; u < 4; u++) {
      const int r = w * 32 + u * 8 + s_row;
      const int cg = s_slot ^ (r & 7);
      GLD_LDS(A + (size_t)(bm0 + r) * lda + k0 + cg * 8, As + (w * 32 + u * 8) * 64);
    }
#pragma unroll
    for (int u = 0; u < NJ; u++) {
      const int r = w * (BN / 4) + u * 8 + s_row;
      const int cg = s_slot ^ (r & 7);
      GLD_LDS(Bt + (size_t)(bn0 + r) * ldb + k0 + cg * 8,
              Bs + (w * (BN / 4) + u * 8) * 64);
    }
    __syncthreads();

#pragma unroll
    for (int ks = 0; ks < 2; ks++) {
      bf16x8 af[4], bfr[NJ];
#pragma unroll
      for (int i = 0; i < 4; i++) {
        const int m = wr * 64 + i * 16 + lr;
        const int slot = (ks * 4 + quad) ^ (m & 7);
        af[i] = *(const bf16x8*)(As + m * 64 + slot * 8);
      }
#pragma unroll
      for (int j = 0; j < NJ; j++) {
        const int n = wc * (BN / 2) + j * 16 + lr;
        const int slot = (ks * 4 + quad) ^ (n & 7);
        bfr[j] = *(const bf16x8*)(Bs + n * 64 + slot * 8);
      }
#pragma unroll
      for (int i = 0; i < 4; i++)
#pragma unroll
        for (int j = 0; j < NJ; j++)
          acc[i][j] =
              __builtin_amdgcn_mfma_f32_16x16x32_bf16(af[i], bfr[j], acc[i][j], 0, 0, 0);
    }
    __syncthreads();
  }

  const int base_m = bm0 + wr * 64 + quad * 4;
  const int base_n = bn0 + wc * (BN / 2) + lr;
#pragma unroll
  for (int i = 0; i < 4; i++) {
#pragma unroll
    for (int j = 0; j < NJ; j++) {
      const int col = base_n + j * 16;
      const float bv = bias ? bias[col] : 0.f;
#pragma unroll
      for (int r = 0; r < 4; r++) {
        const size_t row = base_m + i * 16 + r;
        float v = acc[i][j][r] + bv;
        if (resid) v += resid[row * N + col];
        if (flags & 1) v = fmaxf(v, 0.f);
        if (flags & 2)
          ((uint16_t*)C)[row * N + col] = f2bf(v);
        else
          ((float*)C)[row * N + col] = v;
      }
    }
  }
}

// ---- V transpose: qkv V-region [B*T][3072] -> vtb [(b*H+h)*64+e][T] bf16 ----
__global__ __launch_bounds__(256) void v_transpose(const uint16_t* __restrict__ qkv,
                                                   uint16_t* __restrict__ vtb) {
  __shared__ __align__(16) uint16_t tile[64 * 72];  // [t-local][e]
  const int tid = threadIdx.x;
  const int t0 = blockIdx.x * 64;
  const int bh = blockIdx.y;
  const int b = bh >> 4, h = bh & 15;
  const uint16_t* src = qkv + (size_t)b * T_ * 3072 + 2048 + h * 64;
#pragma unroll
  for (int u = 0; u < 2; u++) {
    const int uu = tid + u * 256;
    const int r = uu >> 3, c = uu & 7;
    *(int4*)(tile + r * 72 + c * 8) =
        *(const int4*)(src + (size_t)(t0 + r) * 3072 + c * 8);
  }
  __syncthreads();
  uint16_t* dst = vtb + ((size_t)bh * 64) * T_ + t0;
#pragma unroll
  for (int u = 0; u < 2; u++) {
    const int uu = tid + u * 256;
    const int e = uu >> 3, c2 = uu & 7;
    union { uint16_t u16[8]; int4 v; } tmp;
#pragma unroll
    for (int jj = 0; jj < 8; jj++) tmp.u16[jj] = tile[(c2 * 8 + jj) * 72 + e];
    *(int4*)(dst + (size_t)e * T_ + c2 * 8) = tmp.v;
  }
}

// ---- per-stage compute for one q-tile (S^T MFMA + static-max softmax + PV) ----
__device__ __forceinline__ void attn_tile_compute(
    const uint16_t* __restrict__ Kb, const uint16_t* __restrict__ Vb,
    uint16_t* __restrict__ Ps, const bf16x8 (&aq)[2][2], f32x4 (&oacc)[2][4],
    float (&l_part)[2], int st, int q0, int w, int quad, int lr) {
  const int lr7 = lr & 7;
  const int row_min_w = q0 + w * 32;

  // S^T = K @ Q^T : frag rows = s (4 sf-frags), cols = m (2 i-frags)
  f32x4 sa[2][4];
#pragma unroll
  for (int i = 0; i < 2; i++)
#pragma unroll
    for (int sf = 0; sf < 4; sf++) sa[i][sf] = f32x4{0.f, 0.f, 0.f, 0.f};
#pragma unroll
  for (int ks = 0; ks < 2; ks++) {
    bf16x8 ak[4];
#pragma unroll
    for (int sf = 0; sf < 4; sf++) {
      const int slot = (ks * 4 + quad) ^ lr7;
      ak[sf] = *(const bf16x8*)(Kb + (sf * 16 + lr) * 64 + slot * 8);
    }
#pragma unroll
    for (int i = 0; i < 2; i++)
#pragma unroll
      for (int sf = 0; sf < 4; sf++)
        sa[i][sf] =
            __builtin_amdgcn_mfma_f32_16x16x32_bf16(ak[sf], aq[i][ks], sa[i][sf], 0, 0, 0);
  }

  // p = exp2(s*log2e/8 - 20*log2e); mask only on the diagonal stage
  const bool diag = (st * 64 + 63 > row_min_w);
  if (diag) {
#pragma unroll
    for (int i = 0; i < 2; i++) {
      const int mrow = q0 + w * 32 + i * 16 + lr;
#pragma unroll
      for (int sf = 0; sf < 4; sf++) {
        const int s0 = st * 64 + sf * 16 + quad * 4;
        float p[4];
#pragma unroll
        for (int r = 0; r < 4; r++) {
          float sv = sa[i][sf][r];
          if (s0 + r > mrow) sv = -1e30f;
          p[r] = exp2f(fmaf(sv, 0.18033688f, -28.8539008f));
          l_part[i] += p[r];
        }
        ushort4 pk;
        pk.x = f2bf(p[0]);
        pk.y = f2bf(p[1]);
        pk.z = f2bf(p[2]);
        pk.w = f2bf(p[3]);
        *(ushort4*)(Ps + (size_t)(w * 32 + i * 16 + lr) * 72 + sf * 16 + quad * 4) = pk;
      }
    }
  } else {
#pragma unroll
    for (int i = 0; i < 2; i++) {
#pragma unroll
      for (int sf = 0; sf < 4; sf++) {
        float p[4];
#pragma unroll
        for (int r = 0; r < 4; r++) {
          p[r] = exp2f(fmaf(sa[i][sf][r], 0.18033688f, -28.8539008f));
          l_part[i] += p[r];
        }
        ushort4 pk;
        pk.x = f2bf(p[0]);
        pk.y = f2bf(p[1]);
        pk.z = f2bf(p[2]);
        pk.w = f2bf(p[3]);
        *(ushort4*)(Ps + (size_t)(w * 32 + i * 16 + lr) * 72 + sf * 16 + quad * 4) = pk;
      }
    }
  }

  // O += P @ V (per-wave LDS region, same-wave write->read)
#pragma unroll
  for (int ks = 0; ks < 2; ks++) {
    bf16x8 ap[2], bv[4];
#pragma unroll
    for (int i = 0; i < 2; i++)
      ap[i] = *(const bf16x8*)(Ps + (size_t)(w * 32 + i * 16 + lr) * 72 + ks * 32 +
                               quad * 8);
#pragma unroll
    for (int j = 0; j < 4; j++) {
      const int slot = (ks * 4 + quad) ^ lr7;
      bv[j] = *(const bf16x8*)(Vb + (j * 16 + lr) * 64 + slot * 8);
    }
#pragma unroll
    for (int i = 0; i < 2; i++)
#pragma unroll
      for (int j = 0; j < 4; j++)
        oacc[i][j] =
            __builtin_amdgcn_mfma_f32_16x16x32_bf16(ap[i], bv[j], oacc[i][j], 0, 0, 0);
  }
}

// ---------------- MFMA flash attention: paired q-tiles + XCD-local K/V ----------
__global__ __launch_bounds__(256) void attn_mfma(const uint16_t* __restrict__ qkv,
                                                 const uint16_t* __restrict__ vtb,
                                                 uint16_t* __restrict__ ctx) {
  __shared__ __align__(16) uint16_t Ks[64 * 64];   // [s][d] swizzled chunks
  __shared__ __align__(16) uint16_t Vt[64 * 64];   // [d][s] swizzled chunks
  __shared__ __align__(16) uint16_t Ps[128 * 72];  // [m][s] plain, padded
  const int tid = threadIdx.x;
  const int lane = tid & 63, w = tid >> 6;
  const int quad = lane >> 4, lr = lane & 15;
  const int pid = blockIdx.x;
  const int bh = pid & 63;         // same XCD for all i of this (b,h)
  const int i_pair = pid >> 6;     // 0..7
  const int b = bh >> 4, h = bh & 15;
  const uint16_t* base = qkv + (size_t)b * T_ * 3072 + h * 64;
  const uint16_t* vbase = vtb + ((size_t)bh * 64) * T_;
  const int s_row = lane >> 3, s_slot = lane & 7;

  const int tqA = i_pair, tqB = 15 - i_pair;
  const int q0A = tqA * 128, q0B = tqB * 128;
  const int nstgA = 2 * tqA + 2, nstgB = 2 * tqB + 2;
  const int nstg = (nstgA > nstgB) ? nstgA : nstgB;

  bf16x8 aqA[2][2], aqB[2][2];
#pragma unroll
  for (int i = 0; i < 2; i++)
#pragma unroll
    for (int ks = 0; ks < 2; ks++) {
      aqA[i][ks] = *(const bf16x8*)(base + (size_t)(q0A + w * 32 + i * 16 + lr) * 3072 +
                                    ks * 32 + quad * 8);
      aqB[i][ks] = *(const bf16x8*)(base + (size_t)(q0B + w * 32 + i * 16 + lr) * 3072 +
                                    ks * 32 + quad * 8);
    }

  f32x4 oaccA[2][4], oaccB[2][4];
#pragma unroll
  for (int i = 0; i < 2; i++)
#pragma unroll
    for (int j = 0; j < 4; j++) {
      oaccA[i][j] = f32x4{0.f, 0.f, 0.f, 0.f};
      oaccB[i][j] = f32x4{0.f, 0.f, 0.f, 0.f};
    }
  float lA[2] = {0.f, 0.f}, lB[2] = {0.f, 0.f};

  const int row_maxA = q0A + w * 32 + 31;
  const int row_maxB = q0B + w * 32 + 31;

  for (int st = 0; st < nstg; st++) {
    __syncthreads();  // prior stage's LDS reads complete
#pragma unroll
    for (int u = 0; u < 2; u++) {
      const int r = w * 16 + u * 8 + s_row;
      const int cg = s_slot ^ (r & 7);
      GLD_LDS(base + 1024 + (size_t)(st * 64 + r) * 3072 + cg * 8,
              Ks + (w * 16 + u * 8) * 64);
      GLD_LDS(vbase + (size_t)r * T_ + st * 64 + cg * 8, Vt + (w * 16 + u * 8) * 64);
    }
    __syncthreads();

    if (st < nstgA && st * 64 <= row_maxA)
      attn_tile_compute(Ks, Vt, Ps, aqA, oaccA, lA, st, q0A, w, quad, lr);
    if (st < nstgB && st * 64 <= row_maxB)
      attn_tile_compute(Ks, Vt, Ps, aqB, oaccB, lB, st, q0B, w, quad, lr);
  }

  // epilogue: reduce l, normalize, store both q-tiles
#pragma unroll
  for (int half = 0; half < 2; half++) {
    const int q0 = half ? q0B : q0A;
    f32x4(&oacc)[2][4] = half ? oaccB : oaccA;
    float* l_part = half ? lB : lA;
    float linv[2];
#pragma unroll
    for (int i = 0; i < 2; i++) {
      float l = l_part[i];
      l += __shfl_xor(l, 16, 64);
      l += __shfl_xor(l, 32, 64);
      linv[i] = 1.f / l;
    }
    uint16_t* ob =
        ctx + ((size_t)b * T_ + q0 + w * 32 + quad * 4) * D_ + h * 64 + lr;
#pragma unroll
    for (int i = 0; i < 2; i++)
#pragma unroll
      for (int r = 0; r < 4; r++) {
        const float inv = __shfl(linv[i], quad * 4 + r, 64);
#pragma unroll
        for (int j = 0; j < 4; j++)
          ob[(size_t)(i * 16 + r) * D_ + j * 16] = f2bf(oacc[i][j][r] * inv);
      }
  }
}

extern "C" void kernel_launch(void* const* d_in, const int* in_sizes, int n_in,
                              void* d_out, int out_size, void* d_ws, size_t ws_size,
                              hipStream_t stream) {
  const float* x = (const float*)d_in[0];
  const float* Wq = (const float*)d_in[1];
  const float* Wk = (const float*)d_in[2];
  const float* Wv = (const float*)d_in[3];
  const float* Wo = (const float*)d_in[4];
  const float* bo = (const float*)d_in[5];
  const float* W1 = (const float*)d_in[6];
  const float* b1 = (const float*)d_in[7];
  const float* W2 = (const float*)d_in[8];
  const float* b2 = (const float*)d_in[9];
  const float* g1 = (const float*)d_in[10];
  const float* be1 = (const float*)d_in[11];
  const float* g2 = (const float*)d_in[12];
  const float* be2 = (const float*)d_in[13];
  float* out = (float*)d_out;

  const size_t MB = 1024ull * 1024ull;
  if (ws_size < 200 * MB) return;
  char* ws = (char*)d_ws;
  uint16_t* hbuf = (uint16_t*)(ws + 0 * MB);    // 16 MB (LN out, reused)
  uint16_t* wqkvt = (uint16_t*)(ws + 16 * MB);  // 6 MB  [3072][1024]
  uint16_t* wot = (uint16_t*)(ws + 22 * MB);    // 2 MB  [1024][1024]
  uint16_t* w1t = (uint16_t*)(ws + 24 * MB);    // 8 MB  [4096][1024]
  uint16_t* w2t = (uint16_t*)(ws + 32 * MB);    // 8 MB  [1024][4096]
  float* x1 = (float*)(ws + 40 * MB);           // 32 MB
  uint16_t* qkvb = (uint16_t*)(ws + 72 * MB);   // 48 MB [8192][3072]
  uint16_t* ctxb = (uint16_t*)(ws + 120 * MB);  // 16 MB [8192][1024]
  uint16_t* vtb = (uint16_t*)(ws + 136 * MB);   // 16 MB (dead before ffb written)
  uint16_t* ffb = (uint16_t*)(ws + 136 * MB);   // 64 MB [8192][4096]

  prep_ln<<<20480, 256, 0, stream>>>(x, g1, be1, hbuf, Wq, Wk, Wv, Wo, W1, W2,
                                     wqkvt, wot, w1t, w2t);
  gemm_bf16<128><<<64 * 24, 256, 0, stream>>>(hbuf, wqkvt, qkvb, nullptr, nullptr,
                                              M_, 3 * D_, D_, D_, D_, 2);
  v_transpose<<<dim3(T_ / 64, B_ * H_), 256, 0, stream>>>(qkvb, vtb);
  attn_mfma<<<512, 256, 0, stream>>>(qkvb, vtb, ctxb);
  gemm_bf16<64><<<64 * 16, 256, 0, stream>>>(ctxb, wot, x1, bo, x, M_, D_, D_, D_,
                                             D_, 0);
  ln_bf16<<<M_, 256, 0, stream>>>(x1, g2, be2, hbuf);
  gemm_bf16<128><<<64 * 32, 256, 0, stream>>>(hbuf, w1t, ffb, b1, nullptr, M_, DFF_,
                                              D_, D_, D_, 1 | 2);
  gemm_bf16<64><<<64 * 16, 256, 0, stream>>>(ffb, w2t, out, b2, x1, M_, D_, DFF_,
                                             DFF_, DFF_, 0);
}